// Round 4
// baseline (1003.277 us; speedup 1.0000x reference)
//
#include <hip/hip_runtime.h>

// 8-layer transformer LM forward. V=128, E=512, L=8, H=8, B=4, T=1024.
// Round 11: mega-fusion of the MLP chains. fused_mlp_ln computes
// LN(residual + relu(A@W1^T+b1)@W2^T+b2) in ONE dispatch per pair (BM=16 row
// strip x full 512 cols, 1024 thr / 16 waves, A+H strips in LDS, W frags read
// straight from L2). Per layer: 8 dispatches -> 4. head+loss_row fused the
// same way (full V=128 row per block). QKV GEMM (BM=128, fused V-transpose)
// and attention (grid 32x16, complementary qt pairing) kept from Round 10.

#define V_  128
#define E_  512
#define L_  8
#define H_  8
#define B_  4
#define T_  1024
#define N_  (B_*T_)    // 4096 tokens
#define DH_ 64
#define E3_ 1536

typedef __attribute__((ext_vector_type(8))) short   bf16x8;   // MFMA A/B frag
typedef __attribute__((ext_vector_type(4))) float   floatx4;  // MFMA C/D frag

// swizzled LDS offset (ushort units): 64-wide rows, 8-elem blocks XORed by row&7
#define SW(row,k8) (((row) << 6) + ((((k8) ^ ((row) & 7))) << 3))

__device__ __forceinline__ unsigned short f2bf(float f) {
    union { float f; unsigned int i; } v; v.f = f;
    unsigned int x = v.i;
    return (unsigned short)((x + 0x7fffu + ((x >> 16) & 1u)) >> 16);  // RNE
}
__device__ __forceinline__ float bf2f(unsigned short u) {
    union { unsigned int i; float f; } v; v.i = ((unsigned int)u) << 16; return v.f;
}
__device__ __forceinline__ void gload_lds16(const void* g, void* l) {
    __builtin_amdgcn_global_load_lds(
        (const __attribute__((address_space(1))) unsigned int*)g,
        (__attribute__((address_space(3))) unsigned int*)l, 16, 0, 0);
}

// ---------------- single-dispatch fp32 -> bf16 weight convert ----------------
#define CVT_N0 6291456   // qkv  L*1536*512
#define CVT_N1 2097152   // per-square L*512*512
#define CVT_TOT (CVT_N0 + 4*CVT_N1 + V_*E_)
__global__ void cvt_all_kernel(const float* __restrict__ s0, const float* __restrict__ s1,
                               const float* __restrict__ s2, const float* __restrict__ s3,
                               const float* __restrict__ s4, const float* __restrict__ s5,
                               unsigned short* __restrict__ dst) {
    long i = (long)(blockIdx.x * blockDim.x + threadIdx.x) * 4;
    if (i >= CVT_TOT) return;
    const float* src; long off;
    if      (i < CVT_N0)               { src = s0; off = i; }
    else if (i < CVT_N0 + CVT_N1)      { src = s1; off = i - CVT_N0; }
    else if (i < CVT_N0 + 2*CVT_N1)    { src = s2; off = i - CVT_N0 - CVT_N1; }
    else if (i < CVT_N0 + 3*CVT_N1)    { src = s3; off = i - CVT_N0 - 2L*CVT_N1; }
    else if (i < CVT_N0 + 4*CVT_N1)    { src = s4; off = i - CVT_N0 - 3L*CVT_N1; }
    else                               { src = s5; off = i - CVT_N0 - 4L*CVT_N1; }
    float4 v = *(const float4*)(src + off);
    ushort4 o; o.x = f2bf(v.x); o.y = f2bf(v.y); o.z = f2bf(v.z); o.w = f2bf(v.w);
    *(ushort4*)(dst + i) = o;
}

// ---------------- embedding: write fp32 + bf16 ----------------
__global__ void embed_kernel(const int* __restrict__ tok, const float* __restrict__ emb,
                             float* __restrict__ xf, unsigned short* __restrict__ xb) {
    int idx = blockIdx.x * blockDim.x + threadIdx.x;
    if (idx >= N_ * E_) return;
    int n = idx >> 9;
    int e = idx & (E_ - 1);
    float v = emb[tok[n] * E_ + e];
    xf[idx] = v; xb[idx] = f2bf(v);
}

// ---------------- QKV GEMM with fused V-transpose (vprep) --------------------
// BM=128. Blocks with n0%192==128 are pure-V blocks: instead of writing qkv_bf
// (dead for V), they write vt_g[bh][d][t] transposed from accumulators and
// reduce the per-ktile column sums into vtile[bh][kt][d].
__global__ __launch_bounds__(256) void gemm_qkv(
    const unsigned short* __restrict__ A, const unsigned short* __restrict__ W,
    const float* __restrict__ bias, unsigned short* __restrict__ Cb,
    unsigned short* __restrict__ vt_g, float* __restrict__ vtile, int K)
{
    __shared__ unsigned short Asm[2][128 * 64];
    __shared__ unsigned short Bsm[2][64 * 64];
    __shared__ float vred[4][64];
    int tid = threadIdx.x;
    int wv = tid >> 6, ln = tid & 63;
    int lquad = ln >> 4, lmod = ln & 15;
    int m0 = blockIdx.y * 128, n0 = blockIdx.x * 64;

    floatx4 acc[2][4] = {};

    auto stage = [&](int k0, int pb) {
        #pragma unroll
        for (int c = 0; c < 4; ++c) {
            int cc = tid + 256 * c;
            int r = cc >> 3, k8s = (cc & 7) ^ (r & 7);
            gload_lds16(A + (size_t)(m0 + r) * K + k0 + 8 * k8s,
                        &Asm[pb][2048 * c + 512 * wv]);
        }
        #pragma unroll
        for (int c = 0; c < 2; ++c) {
            int cc = tid + 256 * c;
            int r = cc >> 3, k8s = (cc & 7) ^ (r & 7);
            gload_lds16(W + (size_t)(n0 + r) * K + k0 + 8 * k8s,
                        &Bsm[pb][2048 * c + 512 * wv]);
        }
    };

    int nt = K >> 6;
    stage(0, 0);
    __syncthreads();
    for (int t = 0; t < nt; ++t) {
        int pb = t & 1;
        if (t + 1 < nt) stage((t + 1) << 6, pb ^ 1);
        #pragma unroll
        for (int ks = 0; ks < 2; ++ks) {
            bf16x8 af[2], bfr[4];
            #pragma unroll
            for (int i = 0; i < 2; ++i)
                af[i] = *(const bf16x8*)&Asm[pb][SW(32 * wv + 16 * i + lmod, ks * 4 + lquad)];
            #pragma unroll
            for (int j = 0; j < 4; ++j)
                bfr[j] = *(const bf16x8*)&Bsm[pb][SW(16 * j + lmod, ks * 4 + lquad)];
            #pragma unroll
            for (int i = 0; i < 2; ++i)
                #pragma unroll
                for (int j = 0; j < 4; ++j)
                    acc[i][j] = __builtin_amdgcn_mfma_f32_16x16x32_bf16(af[i], bfr[j], acc[i][j], 0, 0, 0);
        }
        if (t + 1 < nt) __syncthreads();
    }

    if ((n0 % 192) != 128) {
        #pragma unroll
        for (int i = 0; i < 2; ++i)
            #pragma unroll
            for (int j = 0; j < 4; ++j) {
                int n = n0 + 16 * j + lmod;
                float bj = bias[n];
                #pragma unroll
                for (int v = 0; v < 4; ++v) {
                    int m = m0 + 32 * wv + 16 * i + 4 * lquad + v;
                    Cb[(size_t)m * E3_ + n] = f2bf(acc[i][j][v] + bj);
                }
            }
    } else {
        // pure-V block: write transposed vt_g + vtile sums
        int h = n0 / 192;
        int b = m0 >> 10;
        int bh = b * 8 + h;
        int t0 = m0 & 1023;
        int kt0 = t0 >> 6;
        float sj[4] = {0.f, 0.f, 0.f, 0.f};
        #pragma unroll
        for (int j = 0; j < 4; ++j) {
            float bj = bias[n0 + 16 * j + lmod];
            #pragma unroll
            for (int i = 0; i < 2; ++i) {
                union { unsigned short u[4]; uint2 q; } pk;
                #pragma unroll
                for (int v = 0; v < 4; ++v) {
                    unsigned short r = f2bf(acc[i][j][v] + bj);
                    pk.u[v] = r;
                    sj[j] += bf2f(r);
                }
                int t = t0 + 32 * wv + 16 * i + 4 * lquad;
                *(uint2*)&vt_g[((size_t)(bh * 64 + 16 * j + lmod)) * T_ + t] = pk.q;
            }
        }
        #pragma unroll
        for (int j = 0; j < 4; ++j) {
            sj[j] += __shfl_xor(sj[j], 16);
            sj[j] += __shfl_xor(sj[j], 32);
        }
        if (lquad == 0) {
            #pragma unroll
            for (int j = 0; j < 4; ++j) vred[wv][16 * j + lmod] = sj[j];
        }
        __syncthreads();
        if (tid < 128) {
            int half = tid >> 6, d = tid & 63;
            vtile[((size_t)bh * 16 + kt0 + half) * 64 + d] =
                vred[2 * half][d] + vred[2 * half + 1][d];
        }
    }
}

// ---------------- MFMA flash attention, depth-1 pipelined --------------------
// Grid (32 bh, 16); 2 blocks/CU. qt remap y<8?y:23-y so colocated pairs
// (i, i+256) carry complementary (qt, 15-qt) = 17 tiles. Masked scores are
// ZERO (=> p = 1).
__global__ __launch_bounds__(256) void attn_mfma(const unsigned short* __restrict__ qkv,
                                                 const unsigned short* __restrict__ vt_g,
                                                 const float* __restrict__ vtile,
                                                 unsigned short* __restrict__ outb)
{
    __shared__ unsigned short Qs[64 * 64];       // [q][d] swizzled
    __shared__ unsigned short Ks[2][64 * 64];    // [k][d] swizzled, dbuf
    __shared__ unsigned short Vs[2][64 * 64];    // [d][k] swizzled, dbuf
    __shared__ unsigned short Ps[64 * 64];       // [q][k] swizzled

    int tid = threadIdx.x;
    int wv = tid >> 6, ln = tid & 63;
    int lquad = ln >> 4, lmod = ln & 15;
    int bh = blockIdx.x;
    int y = blockIdx.y;
    int qt = (y < 8) ? y : 23 - y;               // complementary pairing
    int b = bh >> 3, h = bh & 7;
    int q0 = qt * 64;
    const float scale = 0.125f;
    size_t base = (size_t)b * T_ * E3_ + h * 192;

    auto stageKV = [&](int k0, int pb) {
        #pragma unroll
        for (int c = 0; c < 2; ++c) {
            int cc = tid + 256 * c;
            int r = cc >> 3, k8s = (cc & 7) ^ (r & 7);
            gload_lds16(qkv + base + (size_t)(k0 + r) * E3_ + 64 + 8 * k8s,
                        &Ks[pb][2048 * c + 512 * wv]);
            gload_lds16(vt_g + ((size_t)(bh * 64 + r)) * T_ + k0 + 8 * k8s,
                        &Vs[pb][2048 * c + 512 * wv]);
        }
    };

    // stage Q + first K/V tile, then one drain
    #pragma unroll
    for (int c = 0; c < 2; ++c) {
        int cc = tid + 256 * c;
        int r = cc >> 3, k8s = (cc & 7) ^ (r & 7);
        gload_lds16(qkv + base + (size_t)(q0 + r) * E3_ + 8 * k8s, Qs + 2048 * c + 512 * wv);
    }
    stageKV(0, 0);
    __syncthreads();

    float lrow[4] = {0.f, 0.f, 0.f, 0.f};
    floatx4 Oa[4] = {};

    for (int kt = 0; kt <= qt; ++kt) {
        int pb = kt & 1;
        int k0 = kt * 64;
        if (kt < qt) stageKV(k0 + 64, pb ^ 1);    // prefetch next K/V tile

        floatx4 sacc[4] = {};
        #pragma unroll
        for (int ks = 0; ks < 2; ++ks) {
            bf16x8 aq = *(const bf16x8*)&Qs[SW(16 * wv + lmod, ks * 4 + lquad)];
            #pragma unroll
            for (int j = 0; j < 4; ++j) {
                bf16x8 bk = *(const bf16x8*)&Ks[pb][SW(16 * j + lmod, ks * 4 + lquad)];
                sacc[j] = __builtin_amdgcn_mfma_f32_16x16x32_bf16(aq, bk, sacc[j], 0, 0, 0);
            }
        }
        #pragma unroll
        for (int v = 0; v < 4; ++v) {
            int qg = q0 + 16 * wv + 4 * lquad + v;
            int row = 16 * wv + 4 * lquad + v;
            #pragma unroll
            for (int j = 0; j < 4; ++j) {
                int kg = k0 + 16 * j + lmod;
                float p = (kg <= qg) ? __expf(sacc[j][v] * scale) : 1.0f;
                lrow[v] += p;
                int col = 16 * j + lmod;
                Ps[SW(row, col >> 3) + (col & 7)] = f2bf(p);
            }
        }
        // Ps-ready: only DS writes must drain; K/V prefetch stays in flight
        asm volatile("s_waitcnt lgkmcnt(0)" ::: "memory");
        __builtin_amdgcn_s_barrier();

        #pragma unroll
        for (int ks = 0; ks < 2; ++ks) {
            bf16x8 ap = *(const bf16x8*)&Ps[SW(16 * wv + lmod, ks * 4 + lquad)];
            #pragma unroll
            for (int f = 0; f < 4; ++f) {
                bf16x8 bv = *(const bf16x8*)&Vs[pb][SW(16 * f + lmod, ks * 4 + lquad)];
                Oa[f] = __builtin_amdgcn_mfma_f32_16x16x32_bf16(ap, bv, Oa[f], 0, 0, 0);
            }
        }
        if (kt < qt) __syncthreads();  // drain prefetch + WAR on Ps/Ks/Vs
    }

    #pragma unroll
    for (int v = 0; v < 4; ++v)
        #pragma unroll
        for (int msk = 1; msk < 16; msk <<= 1) lrow[v] += __shfl_xor(lrow[v], msk);

    if (qt < 15) {
        float Km = (float)((15 - qt) * 64);
        #pragma unroll
        for (int v = 0; v < 4; ++v) lrow[v] += Km;
        #pragma unroll
        for (int f = 0; f < 4; ++f) {
            float sv = 0.f;
            for (int kt = qt + 1; kt < 16; ++kt)
                sv += vtile[((size_t)bh * 16 + kt) * 64 + 16 * f + lmod];
            #pragma unroll
            for (int v = 0; v < 4; ++v) Oa[f][v] += sv;
        }
    }

    #pragma unroll
    for (int f = 0; f < 4; ++f)
        #pragma unroll
        for (int v = 0; v < 4; ++v) {
            int q = q0 + 16 * wv + 4 * lquad + v;
            outb[(size_t)(b * T_ + q) * E_ + h * DH_ + 16 * f + lmod] = f2bf(Oa[f][v] / lrow[v]);
        }
}

// ---------------- fused MLP + residual + LN ----------------------------------
// out = LN(resF + relu(A@W1^T+b1)@W2^T+b2). BM=16 rows, full 512 cols per
// block; 1024 thr = 16 waves (4/SIMD). A and H strips in LDS (XOR-swizzled);
// W fragments read directly from global (L2-resident, 64B-line coalesced via
// lquad). LN is two-pass (same numerics as the old add_ln kernel).
__global__ __launch_bounds__(1024) void fused_mlp_ln(
    const unsigned short* __restrict__ A, const float* __restrict__ resF,
    const unsigned short* __restrict__ W1, const float* __restrict__ b1,
    const unsigned short* __restrict__ W2, const float* __restrict__ b2,
    const float* __restrict__ lns, const float* __restrict__ lnb,
    float* __restrict__ outF, unsigned short* __restrict__ outB)
{
    __shared__ unsigned short Asl[16 * 512];   // 16 KB, swizzled
    __shared__ unsigned short Hsl[16 * 512];   // 16 KB, swizzled
    __shared__ float red[16][16];
    __shared__ float stat[2][16];

    int tid = threadIdx.x;
    int wv = tid >> 6, ln = tid & 63;
    int lquad = ln >> 4, lmod = ln & 15;
    int m0 = blockIdx.x * 16;

    // stage A strip: wave wv stages row wv; lane ln holds chunk k8d=ln whose
    // swizzled source is ln ^ (wv&7)
    gload_lds16(A + (size_t)(m0 + wv) * E_ + ((ln ^ (wv & 7)) << 3),
                Asl + (wv << 9));
    __syncthreads();

    int c0 = (wv << 5) + lmod, c1 = c0 + 16;   // this lane's two output cols

    // GEMM1: H = relu(A @ W1^T + b1)
    floatx4 a0 = {0.f, 0.f, 0.f, 0.f}, a1 = {0.f, 0.f, 0.f, 0.f};
    #pragma unroll
    for (int ki = 0; ki < 16; ++ki) {
        int k8 = (ki << 2) + lquad;
        bf16x8 af = *(const bf16x8*)&Asl[(lmod << 9) + ((k8 ^ (lmod & 7)) << 3)];
        bf16x8 w0 = *(const bf16x8*)&W1[(size_t)c0 * E_ + (k8 << 3)];
        bf16x8 w1 = *(const bf16x8*)&W1[(size_t)c1 * E_ + (k8 << 3)];
        a0 = __builtin_amdgcn_mfma_f32_16x16x32_bf16(af, w0, a0, 0, 0, 0);
        a1 = __builtin_amdgcn_mfma_f32_16x16x32_bf16(af, w1, a1, 0, 0, 0);
    }
    float bb0 = b1[c0], bb1 = b1[c1];
    #pragma unroll
    for (int v = 0; v < 4; ++v) {
        int row = (lquad << 2) + v;
        Hsl[(row << 9) + (((c0 >> 3) ^ (row & 7)) << 3) + (lmod & 7)] =
            f2bf(fmaxf(a0[v] + bb0, 0.f));
        Hsl[(row << 9) + (((c1 >> 3) ^ (row & 7)) << 3) + (lmod & 7)] =
            f2bf(fmaxf(a1[v] + bb1, 0.f));
    }
    __syncthreads();

    // GEMM2: Y = H @ W2^T + b2, then z = Y + residual
    floatx4 y0 = {0.f, 0.f, 0.f, 0.f}, y1 = {0.f, 0.f, 0.f, 0.f};
    #pragma unroll
    for (int ki = 0; ki < 16; ++ki) {
        int k8 = (ki << 2) + lquad;
        bf16x8 hf = *(const bf16x8*)&Hsl[(lmod << 9) + ((k8 ^ (lmod & 7)) << 3)];
        bf16x8 w0 = *(const bf16x8*)&W2[(size_t)c0 * E_ + (k8 << 3)];
        bf16x8 w1 = *(const bf16x8*)&W2[(size_t)c1 * E_ + (k8 << 3)];
        y0 = __builtin_amdgcn_mfma_f32_16x16x32_bf16(hf, w0, y0, 0, 0, 0);
        y1 = __builtin_amdgcn_mfma_f32_16x16x32_bf16(hf, w1, y1, 0, 0, 0);
    }
    float b20 = b2[c0], b21 = b2[c1];
    float z0[4], z1[4];
    #pragma unroll
    for (int v = 0; v < 4; ++v) {
        int gm = m0 + (lquad << 2) + v;
        z0[v] = y0[v] + b20 + resF[(size_t)gm * E_ + c0];
        z1[v] = y1[v] + b21 + resF[(size_t)gm * E_ + c1];
    }
    // LN pass 1: mean (reduce over lmod in-wave, then across 16 waves via LDS)
    #pragma unroll
    for (int v = 0; v < 4; ++v) {
        float s = z0[v] + z1[v];
        s += __shfl_xor(s, 1); s += __shfl_xor(s, 2);
        s += __shfl_xor(s, 4); s += __shfl_xor(s, 8);
        if (lmod == 0) red[(lquad << 2) + v][wv] = s;
    }
    __syncthreads();
    if (tid < 16) {
        float s = 0.f;
        #pragma unroll
        for (int w = 0; w < 16; ++w) s += red[tid][w];
        stat[0][tid] = s * (1.f / 512.f);
    }
    __syncthreads();
    // LN pass 2: variance
    #pragma unroll
    for (int v = 0; v < 4; ++v) {
        int row = (lquad << 2) + v;
        float mu = stat[0][row];
        float d0 = z0[v] - mu, d1 = z1[v] - mu;
        float s = d0 * d0 + d1 * d1;
        s += __shfl_xor(s, 1); s += __shfl_xor(s, 2);
        s += __shfl_xor(s, 4); s += __shfl_xor(s, 8);
        if (lmod == 0) red[row][wv] = s;
    }
    __syncthreads();
    if (tid < 16) {
        float s = 0.f;
        #pragma unroll
        for (int w = 0; w < 16; ++w) s += red[tid][w];
        stat[1][tid] = rsqrtf(s * (1.f / 512.f) + 1e-5f);
    }
    __syncthreads();
    float s0 = lns[c0], s1 = lns[c1], p0 = lnb[c0], p1 = lnb[c1];
    #pragma unroll
    for (int v = 0; v < 4; ++v) {
        int row = (lquad << 2) + v;
        int gm = m0 + row;
        float mu = stat[0][row], rs = stat[1][row];
        float o0 = (z0[v] - mu) * rs * s0 + p0;
        float o1 = (z1[v] - mu) * rs * s1 + p1;
        outF[(size_t)gm * E_ + c0] = o0;
        outF[(size_t)gm * E_ + c1] = o1;
        outB[(size_t)gm * E_ + c0] = f2bf(o0);
        outB[(size_t)gm * E_ + c1] = f2bf(o1);
    }
}

// ---------------- head GEMM + fused per-row loss ------------------------------
// BM=64, BN=128 (full vocab row per block) -> grid 64. Each wave owns full
// rows, so max/sum/target-gather happen in-wave; writes logits + rowloss.
__global__ __launch_bounds__(256) void head_loss_kernel(
    const unsigned short* __restrict__ A, const unsigned short* __restrict__ W,
    const float* __restrict__ bias, const int* __restrict__ tgt,
    float* __restrict__ out_logits, float* __restrict__ rowloss)
{
    __shared__ unsigned short Asm[2][64 * 64];    // 2 x 8 KB
    __shared__ unsigned short Bsm[2][128 * 64];   // 2 x 16 KB
    int tid = threadIdx.x;
    int wv = tid >> 6, ln = tid & 63;
    int lquad = ln >> 4, lmod = ln & 15;
    int m0 = blockIdx.x * 64;

    floatx4 acc[8] = {};

    auto stage = [&](int k0, int pb) {
        #pragma unroll
        for (int c = 0; c < 2; ++c) {
            int cc = tid + 256 * c;
            int r = cc >> 3, k8s = (cc & 7) ^ (r & 7);
            gload_lds16(A + (size_t)(m0 + r) * E_ + k0 + 8 * k8s,
                        &Asm[pb][2048 * c + 512 * wv]);
        }
        #pragma unroll
        for (int c = 0; c < 4; ++c) {
            int cc = tid + 256 * c;
            int r = cc >> 3, k8s = (cc & 7) ^ (r & 7);
            gload_lds16(W + (size_t)r * E_ + k0 + 8 * k8s,
                        &Bsm[pb][2048 * c + 512 * wv]);
        }
    };

    stage(0, 0);
    __syncthreads();
    for (int t = 0; t < 8; ++t) {
        int pb = t & 1;
        if (t < 7) stage((t + 1) << 6, pb ^ 1);
        #pragma unroll
        for (int ks = 0; ks < 2; ++ks) {
            bf16x8 af = *(const bf16x8*)&Asm[pb][SW(16 * wv + lmod, ks * 4 + lquad)];
            #pragma unroll
            for (int j = 0; j < 8; ++j) {
                bf16x8 bf = *(const bf16x8*)&Bsm[pb][SW(16 * j + lmod, ks * 4 + lquad)];
                acc[j] = __builtin_amdgcn_mfma_f32_16x16x32_bf16(af, bf, acc[j], 0, 0, 0);
            }
        }
        if (t < 7) __syncthreads();
    }

    float bj[8];
    #pragma unroll
    for (int j = 0; j < 8; ++j) bj[j] = bias[16 * j + lmod];
    #pragma unroll
    for (int v = 0; v < 4; ++v) {
        int m = m0 + 16 * wv + 4 * lquad + v;
        float x[8];
        float mx = -1e30f, sx = 0.f;
        #pragma unroll
        for (int j = 0; j < 8; ++j) {
            x[j] = acc[j][v] + bj[j];
            out_logits[(size_t)m * V_ + 16 * j + lmod] = x[j];
            mx = fmaxf(mx, x[j]); sx += x[j];
        }
        #pragma unroll
        for (int msk = 1; msk < 16; msk <<= 1) mx = fmaxf(mx, __shfl_xor(mx, msk));
        float se = 0.f;
        #pragma unroll
        for (int j = 0; j < 8; ++j) se += __expf(x[j] - mx);
        #pragma unroll
        for (int msk = 1; msk < 16; msk <<= 1) {
            se += __shfl_xor(se, msk);
            sx += __shfl_xor(sx, msk);
        }
        int t = tgt[m];                          // uniform within the 16-group
        float cand = 0.f;
        #pragma unroll
        for (int j = 0; j < 8; ++j) cand = ((t >> 4) == j) ? x[j] : cand;
        float xt = __shfl(cand, (ln & 48) | (t & 15));
        if (lmod == 0) {
            float lse = mx + __logf(se);
            rowloss[m] = 0.9f * (lse - xt) + 0.1f * (lse - sx * (1.f / 128.f));
        }
    }
}

__global__ __launch_bounds__(256) void loss_reduce_kernel(
    const float* __restrict__ rowloss, float* __restrict__ out)
{
    int tid = threadIdx.x;
    float sm = 0.f;
    for (int idx = tid; idx < N_; idx += 256) sm += rowloss[idx];
    #pragma unroll
    for (int off = 32; off; off >>= 1) sm += __shfl_down(sm, off, 64);
    __shared__ float red[4];
    int lane = tid & 63, w = tid >> 6;
    if (lane == 0) red[w] = sm;
    __syncthreads();
    if (tid == 0) out[0] = (red[0] + red[1] + red[2] + red[3]) * (1.f / (float)N_);
}

extern "C" void kernel_launch(void* const* d_in, const int* in_sizes, int n_in,
                              void* d_out, int out_size, void* d_ws, size_t ws_size,
                              hipStream_t stream)
{
    (void)in_sizes; (void)n_in; (void)out_size; (void)ws_size;
    const int* toks     = (const int*)d_in[0];
    const int* tgts     = (const int*)d_in[1];
    const float* emb    = (const float*)d_in[2];
    const float* qkv_w  = (const float*)d_in[3];
    const float* qkv_b  = (const float*)d_in[4];
    const float* aff1_w = (const float*)d_in[5];
    const float* aff1_b = (const float*)d_in[6];
    const float* aff2_w = (const float*)d_in[7];
    const float* aff2_b = (const float*)d_in[8];
    const float* ffn1_w = (const float*)d_in[9];
    const float* ffn1_b = (const float*)d_in[10];
    const float* ffn2_w = (const float*)d_in[11];
    const float* ffn2_b = (const float*)d_in[12];
    const float* ln1_s  = (const float*)d_in[13];
    const float* ln1_b  = (const float*)d_in[14];
    const float* ln2_s  = (const float*)d_in[15];
    const float* ln2_b  = (const float*)d_in[16];
    const float* head_w = (const float*)d_in[17];
    const float* head_b = (const float*)d_in[18];

    char* p = (char*)d_ws;
    auto carve = [&](size_t bytes) { char* r = p; p += (bytes + 255) & ~(size_t)255; return (void*)r; };
    unsigned short* wb_all  = (unsigned short*)carve((size_t)CVT_TOT * 2);
    unsigned short* wb_qkv  = wb_all;
    unsigned short* wb_aff1 = wb_qkv  + (size_t)CVT_N0;
    unsigned short* wb_aff2 = wb_aff1 + (size_t)CVT_N1;
    unsigned short* wb_ffn1 = wb_aff2 + (size_t)CVT_N1;
    unsigned short* wb_ffn2 = wb_ffn1 + (size_t)CVT_N1;
    unsigned short* wb_head = wb_ffn2 + (size_t)CVT_N1;
    float*          x_f     = (float*)carve((size_t)N_ * E_ * 4);
    unsigned short* x_b     = (unsigned short*)carve((size_t)N_ * E_ * 2);
    unsigned short* qkv_bf  = (unsigned short*)carve((size_t)N_ * E3_ * 2);
    unsigned short* att_b   = (unsigned short*)carve((size_t)N_ * E_ * 2);
    float*          o1_f    = (float*)carve((size_t)N_ * E_ * 4);
    unsigned short* o1_b    = (unsigned short*)carve((size_t)N_ * E_ * 2);
    float*          rowl    = (float*)carve((size_t)N_ * 4);
    float*          vtile   = (float*)carve((size_t)32 * 16 * 64 * 4);
    unsigned short* vt_g    = (unsigned short*)carve((size_t)32 * 64 * T_ * 2);  // 4 MB

    float* out_logits = (float*)d_out;
    float* out_loss   = out_logits + (size_t)N_ * V_;

    cvt_all_kernel<<<dim3(CVT_TOT / 1024), 256, 0, stream>>>(
        qkv_w, aff1_w, aff2_w, ffn1_w, ffn2_w, head_w, wb_all);

    embed_kernel<<<dim3((N_ * E_) / 256), 256, 0, stream>>>(toks, emb, x_f, x_b);

    for (int l = 0; l < L_; ++l) {
        gemm_qkv<<<dim3(E3_/64, N_/128), 256, 0, stream>>>(
            x_b, wb_qkv + (size_t)l * E3_ * E_, qkv_b + (size_t)l * E3_,
            qkv_bf, vt_g, vtile, E_);
        attn_mfma<<<dim3(32, 16), 256, 0, stream>>>(qkv_bf, vt_g, vtile, att_b);
        fused_mlp_ln<<<dim3(N_/16), 1024, 0, stream>>>(
            att_b, x_f,
            wb_aff1 + (size_t)l * E_ * E_, aff1_b + (size_t)l * E_,
            wb_aff2 + (size_t)l * E_ * E_, aff2_b + (size_t)l * E_,
            ln1_s + (size_t)l * E_, ln1_b + (size_t)l * E_,
            o1_f, o1_b);
        fused_mlp_ln<<<dim3(N_/16), 1024, 0, stream>>>(
            o1_b, o1_f,
            wb_ffn1 + (size_t)l * E_ * E_, ffn1_b + (size_t)l * E_,
            wb_ffn2 + (size_t)l * E_ * E_, ffn2_b + (size_t)l * E_,
            ln2_s + (size_t)l * E_, ln2_b + (size_t)l * E_,
            x_f, x_b);
    }

    head_loss_kernel<<<dim3(N_/64), 256, 0, stream>>>(
        x_b, wb_head, head_b, tgts, out_logits, rowl);
    loss_reduce_kernel<<<dim3(1), 256, 0, stream>>>(rowl, out_loss);
}

// Round 5
// 815.500 us; speedup vs baseline: 1.2303x; 1.2303x over previous
//
#include <hip/hip_runtime.h>

// 8-layer transformer LM forward. V=128, E=512, L=8, H=8, B=4, T=1024.
// Round 12: revert of the BM=16 MLP mega-fusion (L2 weight re-read bound).
// Base = Round 10 (843 us): BM=64 E-square GEMMs (512 blocks = 2/CU), QKV
// BM=128 with fused V-transpose, attention grid (32,16) with complementary qt
// pairing. New: (a) E-square GEMMs process K-chunks in PAIRS with 4 LDS
// buffers (64 KB, still 2 blocks/CU) -> one barrier per 32 MFMAs instead of
// 16; (b) head GEMM + per-row loss fused (verified in R11): deletes the
// 4096-block loss_row dispatch.

#define V_  128
#define E_  512
#define L_  8
#define H_  8
#define B_  4
#define T_  1024
#define N_  (B_*T_)    // 4096 tokens
#define DH_ 64
#define E3_ 1536

typedef __attribute__((ext_vector_type(8))) short   bf16x8;   // MFMA A/B frag
typedef __attribute__((ext_vector_type(4))) float   floatx4;  // MFMA C/D frag

// swizzled LDS offset (ushort units): 64-wide rows, 8-elem blocks XORed by row&7
#define SW(row,k8) (((row) << 6) + ((((k8) ^ ((row) & 7))) << 3))

__device__ __forceinline__ unsigned short f2bf(float f) {
    union { float f; unsigned int i; } v; v.f = f;
    unsigned int x = v.i;
    return (unsigned short)((x + 0x7fffu + ((x >> 16) & 1u)) >> 16);  // RNE
}
__device__ __forceinline__ float bf2f(unsigned short u) {
    union { unsigned int i; float f; } v; v.i = ((unsigned int)u) << 16; return v.f;
}
__device__ __forceinline__ void gload_lds16(const void* g, void* l) {
    __builtin_amdgcn_global_load_lds(
        (const __attribute__((address_space(1))) unsigned int*)g,
        (__attribute__((address_space(3))) unsigned int*)l, 16, 0, 0);
}

// ---------------- single-dispatch fp32 -> bf16 weight convert ----------------
#define CVT_N0 6291456   // qkv  L*1536*512
#define CVT_N1 2097152   // per-square L*512*512
#define CVT_TOT (CVT_N0 + 4*CVT_N1 + V_*E_)
__global__ void cvt_all_kernel(const float* __restrict__ s0, const float* __restrict__ s1,
                               const float* __restrict__ s2, const float* __restrict__ s3,
                               const float* __restrict__ s4, const float* __restrict__ s5,
                               unsigned short* __restrict__ dst) {
    long i = (long)(blockIdx.x * blockDim.x + threadIdx.x) * 4;
    if (i >= CVT_TOT) return;
    const float* src; long off;
    if      (i < CVT_N0)               { src = s0; off = i; }
    else if (i < CVT_N0 + CVT_N1)      { src = s1; off = i - CVT_N0; }
    else if (i < CVT_N0 + 2*CVT_N1)    { src = s2; off = i - CVT_N0 - CVT_N1; }
    else if (i < CVT_N0 + 3*CVT_N1)    { src = s3; off = i - CVT_N0 - 2L*CVT_N1; }
    else if (i < CVT_N0 + 4*CVT_N1)    { src = s4; off = i - CVT_N0 - 3L*CVT_N1; }
    else                               { src = s5; off = i - CVT_N0 - 4L*CVT_N1; }
    float4 v = *(const float4*)(src + off);
    ushort4 o; o.x = f2bf(v.x); o.y = f2bf(v.y); o.z = f2bf(v.z); o.w = f2bf(v.w);
    *(ushort4*)(dst + i) = o;
}

// ---------------- embedding: write fp32 + bf16 ----------------
__global__ void embed_kernel(const int* __restrict__ tok, const float* __restrict__ emb,
                             float* __restrict__ xf, unsigned short* __restrict__ xb) {
    int idx = blockIdx.x * blockDim.x + threadIdx.x;
    if (idx >= N_ * E_) return;
    int n = idx >> 9;
    int e = idx & (E_ - 1);
    float v = emb[tok[n] * E_ + e];
    xf[idx] = v; xb[idx] = f2bf(v);
}

// ---------------- MFMA GEMM: BM=64, BN=64, paired K-chunks -------------------
// 4 LDS buffers; stage the next PAIR of 64-wide K-chunks while computing the
// current pair -> one __syncthreads per 32 MFMAs. 64 KB LDS = 2 blocks/CU.
template<int RELU, int WF, int WB>
__global__ __launch_bounds__(256) void gemm64(
    const unsigned short* __restrict__ A, const unsigned short* __restrict__ W,
    const float* __restrict__ bias, float* __restrict__ Cf, unsigned short* __restrict__ Cb,
    int M, int Nout, int K)
{
    __shared__ unsigned short Asm[4][64 * 64];   // 4 x 8 KB, swizzled
    __shared__ unsigned short Bsm[4][64 * 64];   // 4 x 8 KB, swizzled
    int tid = threadIdx.x;
    int wv = tid >> 6, ln = tid & 63;
    int lquad = ln >> 4, lmod = ln & 15;
    int m0 = blockIdx.y * 64, n0 = blockIdx.x * 64;

    floatx4 acc[4] = {};

    auto stage = [&](int k0, int s) {
        // lane fetches the chunk whose swizzled home is its fixed LDS slot:
        // k8_src = k8_dest ^ (row & 7)
        #pragma unroll
        for (int c = 0; c < 2; ++c) {
            int cc = tid + 256 * c;
            int r = cc >> 3, k8s = (cc & 7) ^ (r & 7);
            gload_lds16(A + (size_t)(m0 + r) * K + k0 + 8 * k8s,
                        &Asm[s][2048 * c + 512 * wv]);
        }
        #pragma unroll
        for (int c = 0; c < 2; ++c) {
            int cc = tid + 256 * c;
            int r = cc >> 3, k8s = (cc & 7) ^ (r & 7);
            gload_lds16(W + (size_t)(n0 + r) * K + k0 + 8 * k8s,
                        &Bsm[s][2048 * c + 512 * wv]);
        }
    };

    int np = K >> 7;                       // pairs of 64-chunks (K=512 -> 4)
    stage(0, 0);
    stage(64, 1);
    __syncthreads();

    for (int t = 0; t < np; ++t) {
        if (t + 1 < np) {
            stage((2 * t + 2) << 6, (2 * t + 2) & 3);
            stage((2 * t + 3) << 6, (2 * t + 3) & 3);
        }
        #pragma unroll
        for (int half = 0; half < 2; ++half) {
            int s = (2 * t + half) & 3;
            #pragma unroll
            for (int ks = 0; ks < 2; ++ks) {
                bf16x8 af = *(const bf16x8*)&Asm[s][SW(16 * wv + lmod, ks * 4 + lquad)];
                #pragma unroll
                for (int j = 0; j < 4; ++j) {
                    bf16x8 bfr = *(const bf16x8*)&Bsm[s][SW(16 * j + lmod, ks * 4 + lquad)];
                    acc[j] = __builtin_amdgcn_mfma_f32_16x16x32_bf16(af, bfr, acc[j], 0, 0, 0);
                }
            }
        }
        if (t + 1 < np) __syncthreads();   // drains next-pair prefetch + WAR
    }

    #pragma unroll
    for (int j = 0; j < 4; ++j) {
        int n = n0 + 16 * j + lmod;
        float bj = bias[n];
        #pragma unroll
        for (int v = 0; v < 4; ++v) {
            int m = m0 + 16 * wv + 4 * lquad + v;
            float val = acc[j][v] + bj;
            if (RELU) val = fmaxf(val, 0.f);
            if (WF) Cf[(size_t)m * Nout + n] = val;
            if (WB) Cb[(size_t)m * Nout + n] = f2bf(val);
        }
    }
}

// ---------------- QKV GEMM with fused V-transpose (vprep) --------------------
// BM=128. Blocks with n0%192==128 are pure-V blocks: instead of writing qkv_bf
// (dead for V), they write vt_g[bh][d][t] transposed from accumulators and
// reduce the per-ktile column sums into vtile[bh][kt][d].
__global__ __launch_bounds__(256) void gemm_qkv(
    const unsigned short* __restrict__ A, const unsigned short* __restrict__ W,
    const float* __restrict__ bias, unsigned short* __restrict__ Cb,
    unsigned short* __restrict__ vt_g, float* __restrict__ vtile, int K)
{
    __shared__ unsigned short Asm[2][128 * 64];
    __shared__ unsigned short Bsm[2][64 * 64];
    __shared__ float vred[4][64];
    int tid = threadIdx.x;
    int wv = tid >> 6, ln = tid & 63;
    int lquad = ln >> 4, lmod = ln & 15;
    int m0 = blockIdx.y * 128, n0 = blockIdx.x * 64;

    floatx4 acc[2][4] = {};

    auto stage = [&](int k0, int pb) {
        #pragma unroll
        for (int c = 0; c < 4; ++c) {
            int cc = tid + 256 * c;
            int r = cc >> 3, k8s = (cc & 7) ^ (r & 7);
            gload_lds16(A + (size_t)(m0 + r) * K + k0 + 8 * k8s,
                        &Asm[pb][2048 * c + 512 * wv]);
        }
        #pragma unroll
        for (int c = 0; c < 2; ++c) {
            int cc = tid + 256 * c;
            int r = cc >> 3, k8s = (cc & 7) ^ (r & 7);
            gload_lds16(W + (size_t)(n0 + r) * K + k0 + 8 * k8s,
                        &Bsm[pb][2048 * c + 512 * wv]);
        }
    };

    int nt = K >> 6;
    stage(0, 0);
    __syncthreads();
    for (int t = 0; t < nt; ++t) {
        int pb = t & 1;
        if (t + 1 < nt) stage((t + 1) << 6, pb ^ 1);
        #pragma unroll
        for (int ks = 0; ks < 2; ++ks) {
            bf16x8 af[2], bfr[4];
            #pragma unroll
            for (int i = 0; i < 2; ++i)
                af[i] = *(const bf16x8*)&Asm[pb][SW(32 * wv + 16 * i + lmod, ks * 4 + lquad)];
            #pragma unroll
            for (int j = 0; j < 4; ++j)
                bfr[j] = *(const bf16x8*)&Bsm[pb][SW(16 * j + lmod, ks * 4 + lquad)];
            #pragma unroll
            for (int i = 0; i < 2; ++i)
                #pragma unroll
                for (int j = 0; j < 4; ++j)
                    acc[i][j] = __builtin_amdgcn_mfma_f32_16x16x32_bf16(af[i], bfr[j], acc[i][j], 0, 0, 0);
        }
        if (t + 1 < nt) __syncthreads();
    }

    if ((n0 % 192) != 128) {
        #pragma unroll
        for (int i = 0; i < 2; ++i)
            #pragma unroll
            for (int j = 0; j < 4; ++j) {
                int n = n0 + 16 * j + lmod;
                float bj = bias[n];
                #pragma unroll
                for (int v = 0; v < 4; ++v) {
                    int m = m0 + 32 * wv + 16 * i + 4 * lquad + v;
                    Cb[(size_t)m * E3_ + n] = f2bf(acc[i][j][v] + bj);
                }
            }
    } else {
        // pure-V block: write transposed vt_g + vtile sums
        int h = n0 / 192;
        int b = m0 >> 10;
        int bh = b * 8 + h;
        int t0 = m0 & 1023;
        int kt0 = t0 >> 6;
        float sj[4] = {0.f, 0.f, 0.f, 0.f};
        #pragma unroll
        for (int j = 0; j < 4; ++j) {
            float bj = bias[n0 + 16 * j + lmod];
            #pragma unroll
            for (int i = 0; i < 2; ++i) {
                union { unsigned short u[4]; uint2 q; } pk;
                #pragma unroll
                for (int v = 0; v < 4; ++v) {
                    unsigned short r = f2bf(acc[i][j][v] + bj);
                    pk.u[v] = r;
                    sj[j] += bf2f(r);
                }
                int t = t0 + 32 * wv + 16 * i + 4 * lquad;
                *(uint2*)&vt_g[((size_t)(bh * 64 + 16 * j + lmod)) * T_ + t] = pk.q;
            }
        }
        #pragma unroll
        for (int j = 0; j < 4; ++j) {
            sj[j] += __shfl_xor(sj[j], 16);
            sj[j] += __shfl_xor(sj[j], 32);
        }
        if (lquad == 0) {
            #pragma unroll
            for (int j = 0; j < 4; ++j) vred[wv][16 * j + lmod] = sj[j];
        }
        __syncthreads();
        if (tid < 128) {
            int half = tid >> 6, d = tid & 63;
            vtile[((size_t)bh * 16 + kt0 + half) * 64 + d] =
                vred[2 * half][d] + vred[2 * half + 1][d];
        }
    }
}

// ---------------- MFMA flash attention, depth-1 pipelined --------------------
// Grid (32 bh, 16); 2 blocks/CU. qt remap y<8?y:23-y so colocated pairs
// (i, i+256) carry complementary (qt, 15-qt) = 17 tiles. Masked scores are
// ZERO (=> p = 1).
__global__ __launch_bounds__(256) void attn_mfma(const unsigned short* __restrict__ qkv,
                                                 const unsigned short* __restrict__ vt_g,
                                                 const float* __restrict__ vtile,
                                                 unsigned short* __restrict__ outb)
{
    __shared__ unsigned short Qs[64 * 64];       // [q][d] swizzled
    __shared__ unsigned short Ks[2][64 * 64];    // [k][d] swizzled, dbuf
    __shared__ unsigned short Vs[2][64 * 64];    // [d][k] swizzled, dbuf
    __shared__ unsigned short Ps[64 * 64];       // [q][k] swizzled

    int tid = threadIdx.x;
    int wv = tid >> 6, ln = tid & 63;
    int lquad = ln >> 4, lmod = ln & 15;
    int bh = blockIdx.x;
    int y = blockIdx.y;
    int qt = (y < 8) ? y : 23 - y;               // complementary pairing
    int b = bh >> 3, h = bh & 7;
    int q0 = qt * 64;
    const float scale = 0.125f;
    size_t base = (size_t)b * T_ * E3_ + h * 192;

    auto stageKV = [&](int k0, int pb) {
        #pragma unroll
        for (int c = 0; c < 2; ++c) {
            int cc = tid + 256 * c;
            int r = cc >> 3, k8s = (cc & 7) ^ (r & 7);
            gload_lds16(qkv + base + (size_t)(k0 + r) * E3_ + 64 + 8 * k8s,
                        &Ks[pb][2048 * c + 512 * wv]);
            gload_lds16(vt_g + ((size_t)(bh * 64 + r)) * T_ + k0 + 8 * k8s,
                        &Vs[pb][2048 * c + 512 * wv]);
        }
    };

    // stage Q + first K/V tile, then one drain
    #pragma unroll
    for (int c = 0; c < 2; ++c) {
        int cc = tid + 256 * c;
        int r = cc >> 3, k8s = (cc & 7) ^ (r & 7);
        gload_lds16(qkv + base + (size_t)(q0 + r) * E3_ + 8 * k8s, Qs + 2048 * c + 512 * wv);
    }
    stageKV(0, 0);
    __syncthreads();

    float lrow[4] = {0.f, 0.f, 0.f, 0.f};
    floatx4 Oa[4] = {};

    for (int kt = 0; kt <= qt; ++kt) {
        int pb = kt & 1;
        int k0 = kt * 64;
        if (kt < qt) stageKV(k0 + 64, pb ^ 1);    // prefetch next K/V tile

        floatx4 sacc[4] = {};
        #pragma unroll
        for (int ks = 0; ks < 2; ++ks) {
            bf16x8 aq = *(const bf16x8*)&Qs[SW(16 * wv + lmod, ks * 4 + lquad)];
            #pragma unroll
            for (int j = 0; j < 4; ++j) {
                bf16x8 bk = *(const bf16x8*)&Ks[pb][SW(16 * j + lmod, ks * 4 + lquad)];
                sacc[j] = __builtin_amdgcn_mfma_f32_16x16x32_bf16(aq, bk, sacc[j], 0, 0, 0);
            }
        }
        #pragma unroll
        for (int v = 0; v < 4; ++v) {
            int qg = q0 + 16 * wv + 4 * lquad + v;
            int row = 16 * wv + 4 * lquad + v;
            #pragma unroll
            for (int j = 0; j < 4; ++j) {
                int kg = k0 + 16 * j + lmod;
                float p = (kg <= qg) ? __expf(sacc[j][v] * scale) : 1.0f;
                lrow[v] += p;
                int col = 16 * j + lmod;
                Ps[SW(row, col >> 3) + (col & 7)] = f2bf(p);
            }
        }
        // Ps-ready: only DS writes must drain; K/V prefetch stays in flight
        asm volatile("s_waitcnt lgkmcnt(0)" ::: "memory");
        __builtin_amdgcn_s_barrier();

        #pragma unroll
        for (int ks = 0; ks < 2; ++ks) {
            bf16x8 ap = *(const bf16x8*)&Ps[SW(16 * wv + lmod, ks * 4 + lquad)];
            #pragma unroll
            for (int f = 0; f < 4; ++f) {
                bf16x8 bv = *(const bf16x8*)&Vs[pb][SW(16 * f + lmod, ks * 4 + lquad)];
                Oa[f] = __builtin_amdgcn_mfma_f32_16x16x32_bf16(ap, bv, Oa[f], 0, 0, 0);
            }
        }
        if (kt < qt) __syncthreads();  // drain prefetch + WAR on Ps/Ks/Vs
    }

    #pragma unroll
    for (int v = 0; v < 4; ++v)
        #pragma unroll
        for (int msk = 1; msk < 16; msk <<= 1) lrow[v] += __shfl_xor(lrow[v], msk);

    if (qt < 15) {
        float Km = (float)((15 - qt) * 64);
        #pragma unroll
        for (int v = 0; v < 4; ++v) lrow[v] += Km;
        #pragma unroll
        for (int f = 0; f < 4; ++f) {
            float sv = 0.f;
            for (int kt = qt + 1; kt < 16; ++kt)
                sv += vtile[((size_t)bh * 16 + kt) * 64 + 16 * f + lmod];
            #pragma unroll
            for (int v = 0; v < 4; ++v) Oa[f][v] += sv;
        }
    }

    #pragma unroll
    for (int f = 0; f < 4; ++f)
        #pragma unroll
        for (int v = 0; v < 4; ++v) {
            int q = q0 + 16 * wv + 4 * lquad + v;
            outb[(size_t)(b * T_ + q) * E_ + h * DH_ + 16 * f + lmod] = f2bf(Oa[f][v] / lrow[v]);
        }
}

// ---------------- residual add + LN: wave-per-row ----------------
__global__ __launch_bounds__(256) void add_ln_kernel(
    const float* __restrict__ a, const float* __restrict__ r,
    const float* __restrict__ s, const float* __restrict__ bpar,
    float* __restrict__ outF, unsigned short* __restrict__ outB)
{
    int tid = threadIdx.x, wv = tid >> 6, ln = tid & 63;
    int n = blockIdx.x * 4 + wv;
    int e = ln * 8;
    size_t base = (size_t)n * E_ + e;
    float4 a0 = *(const float4*)&a[base],     a1 = *(const float4*)&a[base + 4];
    float4 r0 = *(const float4*)&r[base],     r1 = *(const float4*)&r[base + 4];
    float v[8] = {a0.x + r0.x, a0.y + r0.y, a0.z + r0.z, a0.w + r0.w,
                  a1.x + r1.x, a1.y + r1.y, a1.z + r1.z, a1.w + r1.w};

    float sm = 0.f;
    #pragma unroll
    for (int i = 0; i < 8; ++i) sm += v[i];
    #pragma unroll
    for (int msk = 1; msk < 64; msk <<= 1) sm += __shfl_xor(sm, msk);
    float mu = sm * (1.f / 512.f);

    float ss = 0.f;
    #pragma unroll
    for (int i = 0; i < 8; ++i) { v[i] -= mu; ss += v[i] * v[i]; }
    #pragma unroll
    for (int msk = 1; msk < 64; msk <<= 1) ss += __shfl_xor(ss, msk);
    float rstd = rsqrtf(ss * (1.f / 512.f) + 1e-5f);

    float4 sc0 = *(const float4*)&s[e],    sc1 = *(const float4*)&s[e + 4];
    float4 bp0 = *(const float4*)&bpar[e], bp1 = *(const float4*)&bpar[e + 4];
    float o[8];
    o[0] = v[0] * rstd * sc0.x + bp0.x; o[1] = v[1] * rstd * sc0.y + bp0.y;
    o[2] = v[2] * rstd * sc0.z + bp0.z; o[3] = v[3] * rstd * sc0.w + bp0.w;
    o[4] = v[4] * rstd * sc1.x + bp1.x; o[5] = v[5] * rstd * sc1.y + bp1.y;
    o[6] = v[6] * rstd * sc1.z + bp1.z; o[7] = v[7] * rstd * sc1.w + bp1.w;
    *(float4*)&outF[base]     = make_float4(o[0], o[1], o[2], o[3]);
    *(float4*)&outF[base + 4] = make_float4(o[4], o[5], o[6], o[7]);
    union { unsigned short u[8]; uint4 q; } pk;
    #pragma unroll
    for (int i = 0; i < 8; ++i) pk.u[i] = f2bf(o[i]);
    *(uint4*)&outB[base] = pk.q;
}

// ---------------- head GEMM + fused per-row loss ------------------------------
// BM=64, BN=128 (full vocab row per block) -> grid 64. Each wave owns full
// rows, so max/sum/target-gather happen in-wave; writes logits + rowloss.
__global__ __launch_bounds__(256) void head_loss_kernel(
    const unsigned short* __restrict__ A, const unsigned short* __restrict__ W,
    const float* __restrict__ bias, const int* __restrict__ tgt,
    float* __restrict__ out_logits, float* __restrict__ rowloss)
{
    __shared__ unsigned short Asm[2][64 * 64];    // 2 x 8 KB
    __shared__ unsigned short Bsm[2][128 * 64];   // 2 x 16 KB
    int tid = threadIdx.x;
    int wv = tid >> 6, ln = tid & 63;
    int lquad = ln >> 4, lmod = ln & 15;
    int m0 = blockIdx.x * 64;

    floatx4 acc[8] = {};

    auto stage = [&](int k0, int pb) {
        #pragma unroll
        for (int c = 0; c < 2; ++c) {
            int cc = tid + 256 * c;
            int r = cc >> 3, k8s = (cc & 7) ^ (r & 7);
            gload_lds16(A + (size_t)(m0 + r) * E_ + k0 + 8 * k8s,
                        &Asm[pb][2048 * c + 512 * wv]);
        }
        #pragma unroll
        for (int c = 0; c < 4; ++c) {
            int cc = tid + 256 * c;
            int r = cc >> 3, k8s = (cc & 7) ^ (r & 7);
            gload_lds16(W + (size_t)r * E_ + k0 + 8 * k8s,
                        &Bsm[pb][2048 * c + 512 * wv]);
        }
    };

    stage(0, 0);
    __syncthreads();
    for (int t = 0; t < 8; ++t) {
        int pb = t & 1;
        if (t < 7) stage((t + 1) << 6, pb ^ 1);
        #pragma unroll
        for (int ks = 0; ks < 2; ++ks) {
            bf16x8 af = *(const bf16x8*)&Asm[pb][SW(16 * wv + lmod, ks * 4 + lquad)];
            #pragma unroll
            for (int j = 0; j < 8; ++j) {
                bf16x8 bf = *(const bf16x8*)&Bsm[pb][SW(16 * j + lmod, ks * 4 + lquad)];
                acc[j] = __builtin_amdgcn_mfma_f32_16x16x32_bf16(af, bf, acc[j], 0, 0, 0);
            }
        }
        if (t < 7) __syncthreads();
    }

    float bj[8];
    #pragma unroll
    for (int j = 0; j < 8; ++j) bj[j] = bias[16 * j + lmod];
    #pragma unroll
    for (int v = 0; v < 4; ++v) {
        int m = m0 + 16 * wv + 4 * lquad + v;
        float x[8];
        float mx = -1e30f, sx = 0.f;
        #pragma unroll
        for (int j = 0; j < 8; ++j) {
            x[j] = acc[j][v] + bj[j];
            out_logits[(size_t)m * V_ + 16 * j + lmod] = x[j];
            mx = fmaxf(mx, x[j]); sx += x[j];
        }
        #pragma unroll
        for (int msk = 1; msk < 16; msk <<= 1) mx = fmaxf(mx, __shfl_xor(mx, msk));
        float se = 0.f;
        #pragma unroll
        for (int j = 0; j < 8; ++j) se += __expf(x[j] - mx);
        #pragma unroll
        for (int msk = 1; msk < 16; msk <<= 1) {
            se += __shfl_xor(se, msk);
            sx += __shfl_xor(sx, msk);
        }
        int t = tgt[m];                          // uniform within the 16-group
        float cand = 0.f;
        #pragma unroll
        for (int j = 0; j < 8; ++j) cand = ((t >> 4) == j) ? x[j] : cand;
        float xt = __shfl(cand, (ln & 48) | (t & 15));
        if (lmod == 0) {
            float lse = mx + __logf(se);
            rowloss[m] = 0.9f * (lse - xt) + 0.1f * (lse - sx * (1.f / 128.f));
        }
    }
}

__global__ __launch_bounds__(256) void loss_reduce_kernel(
    const float* __restrict__ rowloss, float* __restrict__ out)
{
    int tid = threadIdx.x;
    float sm = 0.f;
    for (int idx = tid; idx < N_; idx += 256) sm += rowloss[idx];
    #pragma unroll
    for (int off = 32; off; off >>= 1) sm += __shfl_down(sm, off, 64);
    __shared__ float red[4];
    int lane = tid & 63, w = tid >> 6;
    if (lane == 0) red[w] = sm;
    __syncthreads();
    if (tid == 0) out[0] = (red[0] + red[1] + red[2] + red[3]) * (1.f / (float)N_);
}

extern "C" void kernel_launch(void* const* d_in, const int* in_sizes, int n_in,
                              void* d_out, int out_size, void* d_ws, size_t ws_size,
                              hipStream_t stream)
{
    (void)in_sizes; (void)n_in; (void)out_size; (void)ws_size;
    const int* toks     = (const int*)d_in[0];
    const int* tgts     = (const int*)d_in[1];
    const float* emb    = (const float*)d_in[2];
    const float* qkv_w  = (const float*)d_in[3];
    const float* qkv_b  = (const float*)d_in[4];
    const float* aff1_w = (const float*)d_in[5];
    const float* aff1_b = (const float*)d_in[6];
    const float* aff2_w = (const float*)d_in[7];
    const float* aff2_b = (const float*)d_in[8];
    const float* ffn1_w = (const float*)d_in[9];
    const float* ffn1_b = (const float*)d_in[10];
    const float* ffn2_w = (const float*)d_in[11];
    const float* ffn2_b = (const float*)d_in[12];
    const float* ln1_s  = (const float*)d_in[13];
    const float* ln1_b  = (const float*)d_in[14];
    const float* ln2_s  = (const float*)d_in[15];
    const float* ln2_b  = (const float*)d_in[16];
    const float* head_w = (const float*)d_in[17];
    const float* head_b = (const float*)d_in[18];

    char* p = (char*)d_ws;
    auto carve = [&](size_t bytes) { char* r = p; p += (bytes + 255) & ~(size_t)255; return (void*)r; };
    unsigned short* wb_all  = (unsigned short*)carve((size_t)CVT_TOT * 2);
    unsigned short* wb_qkv  = wb_all;
    unsigned short* wb_aff1 = wb_qkv  + (size_t)CVT_N0;
    unsigned short* wb_aff2 = wb_aff1 + (size_t)CVT_N1;
    unsigned short* wb_ffn1 = wb_aff2 + (size_t)CVT_N1;
    unsigned short* wb_ffn2 = wb_ffn1 + (size_t)CVT_N1;
    unsigned short* wb_head = wb_ffn2 + (size_t)CVT_N1;
    float*          x_f     = (float*)carve((size_t)N_ * E_ * 4);
    unsigned short* x_b     = (unsigned short*)carve((size_t)N_ * E_ * 2);
    unsigned short* qkv_bf  = (unsigned short*)carve((size_t)N_ * E3_ * 2);
    unsigned short* att_b   = (unsigned short*)carve((size_t)N_ * E_ * 2);
    unsigned short* h_b     = (unsigned short*)carve((size_t)N_ * E_ * 2);
    float*          y_f     = (float*)carve((size_t)N_ * E_ * 4);
    float*          o1_f    = (float*)carve((size_t)N_ * E_ * 4);
    unsigned short* o1_b    = (unsigned short*)carve((size_t)N_ * E_ * 2);
    float*          rowl    = (float*)carve((size_t)N_ * 4);
    float*          vtile   = (float*)carve((size_t)32 * 16 * 64 * 4);
    unsigned short* vt_g    = (unsigned short*)carve((size_t)32 * 64 * T_ * 2);  // 4 MB

    float* out_logits = (float*)d_out;
    float* out_loss   = out_logits + (size_t)N_ * V_;

    cvt_all_kernel<<<dim3(CVT_TOT / 1024), 256, 0, stream>>>(
        qkv_w, aff1_w, aff2_w, ffn1_w, ffn2_w, head_w, wb_all);

    embed_kernel<<<dim3((N_ * E_) / 256), 256, 0, stream>>>(toks, emb, x_f, x_b);

    for (int l = 0; l < L_; ++l) {
        gemm_qkv<<<dim3(E3_/64, N_/128), 256, 0, stream>>>(
            x_b, wb_qkv + (size_t)l * E3_ * E_, qkv_b + (size_t)l * E3_,
            qkv_bf, vt_g, vtile, E_);
        attn_mfma<<<dim3(32, 16), 256, 0, stream>>>(qkv_bf, vt_g, vtile, att_b);
        gemm64<1,0,1><<<dim3(E_/64, N_/64), 256, 0, stream>>>(
            att_b, wb_aff1 + (size_t)l * E_ * E_, aff1_b + (size_t)l * E_,
            nullptr, h_b, N_, E_, E_);
        gemm64<0,1,0><<<dim3(E_/64, N_/64), 256, 0, stream>>>(
            h_b, wb_aff2 + (size_t)l * E_ * E_, aff2_b + (size_t)l * E_,
            y_f, nullptr, N_, E_, E_);
        add_ln_kernel<<<dim3(N_/4), 256, 0, stream>>>(
            y_f, x_f, ln1_s + (size_t)l * E_, ln1_b + (size_t)l * E_, o1_f, o1_b);
        gemm64<1,0,1><<<dim3(E_/64, N_/64), 256, 0, stream>>>(
            o1_b, wb_ffn1 + (size_t)l * E_ * E_, ffn1_b + (size_t)l * E_,
            nullptr, h_b, N_, E_, E_);
        gemm64<0,1,0><<<dim3(E_/64, N_/64), 256, 0, stream>>>(
            h_b, wb_ffn2 + (size_t)l * E_ * E_, ffn2_b + (size_t)l * E_,
            y_f, nullptr, N_, E_, E_);
        add_ln_kernel<<<dim3(N_/4), 256, 0, stream>>>(
            o1_f, y_f, ln2_s + (size_t)l * E_, ln2_b + (size_t)l * E_, x_f, x_b);
    }

    head_loss_kernel<<<dim3(N_/64), 256, 0, stream>>>(
        x_b, wb_head, head_b, tgts, out_logits, rowl);
    loss_reduce_kernel<<<dim3(1), 256, 0, stream>>>(rowl, out_loss);
}

// Round 6
// 796.831 us; speedup vs baseline: 1.2591x; 1.0234x over previous
//
#include <hip/hip_runtime.h>

// 8-layer transformer LM forward. V=128, E=512, L=8, H=8, B=4, T=1024.
// Round 13: (a) XCD-grouped block remap in gemm64 + gemm_qkv: all n-blocks of
// one m-strip land on the SAME XCD (flat%8 heuristic), so shared A-strips are
// fetched once per XCD instead of 8x from L3 (gemm64: ~64MB -> ~8MB re-read
// traffic; qkv: ~144MB -> ~16MB). Attention is naturally grouped (flat%8 =
// bh%8). (b) attn: mid-ktile s_barrier dropped -- Ps is wave-private, so
// lgkmcnt(0) alone suffices. Base = Round 12 (815 us): paired-K gemm64,
// fused-vprep QKV, complementary-paired attention, fused head+loss.

#define V_  128
#define E_  512
#define L_  8
#define H_  8
#define B_  4
#define T_  1024
#define N_  (B_*T_)    // 4096 tokens
#define DH_ 64
#define E3_ 1536

typedef __attribute__((ext_vector_type(8))) short   bf16x8;   // MFMA A/B frag
typedef __attribute__((ext_vector_type(4))) float   floatx4;  // MFMA C/D frag

// swizzled LDS offset (ushort units): 64-wide rows, 8-elem blocks XORed by row&7
#define SW(row,k8) (((row) << 6) + ((((k8) ^ ((row) & 7))) << 3))

__device__ __forceinline__ unsigned short f2bf(float f) {
    union { float f; unsigned int i; } v; v.f = f;
    unsigned int x = v.i;
    return (unsigned short)((x + 0x7fffu + ((x >> 16) & 1u)) >> 16);  // RNE
}
__device__ __forceinline__ float bf2f(unsigned short u) {
    union { unsigned int i; float f; } v; v.i = ((unsigned int)u) << 16; return v.f;
}
__device__ __forceinline__ void gload_lds16(const void* g, void* l) {
    __builtin_amdgcn_global_load_lds(
        (const __attribute__((address_space(1))) unsigned int*)g,
        (__attribute__((address_space(3))) unsigned int*)l, 16, 0, 0);
}

// XCD-grouped remap: grid (nx, ny), ny%8==0. Returns (mstrip, nblk) such that
// all nx n-blocks of one m-strip share one XCD (assignment heuristic: flat%8).
__device__ __forceinline__ void xcd_remap(int& mstrip, int& nblk) {
    int nx = gridDim.x;
    int flat = blockIdx.y * nx + blockIdx.x;
    int xcd = flat & 7;
    int j = flat >> 3;                    // index within this XCD
    int per_xcd = gridDim.y >> 3;         // m-strips per XCD
    mstrip = xcd * per_xcd + j / nx;
    nblk = j % nx;
}

// ---------------- single-dispatch fp32 -> bf16 weight convert ----------------
#define CVT_N0 6291456   // qkv  L*1536*512
#define CVT_N1 2097152   // per-square L*512*512
#define CVT_TOT (CVT_N0 + 4*CVT_N1 + V_*E_)
__global__ void cvt_all_kernel(const float* __restrict__ s0, const float* __restrict__ s1,
                               const float* __restrict__ s2, const float* __restrict__ s3,
                               const float* __restrict__ s4, const float* __restrict__ s5,
                               unsigned short* __restrict__ dst) {
    long i = (long)(blockIdx.x * blockDim.x + threadIdx.x) * 4;
    if (i >= CVT_TOT) return;
    const float* src; long off;
    if      (i < CVT_N0)               { src = s0; off = i; }
    else if (i < CVT_N0 + CVT_N1)      { src = s1; off = i - CVT_N0; }
    else if (i < CVT_N0 + 2*CVT_N1)    { src = s2; off = i - CVT_N0 - CVT_N1; }
    else if (i < CVT_N0 + 3*CVT_N1)    { src = s3; off = i - CVT_N0 - 2L*CVT_N1; }
    else if (i < CVT_N0 + 4*CVT_N1)    { src = s4; off = i - CVT_N0 - 3L*CVT_N1; }
    else                               { src = s5; off = i - CVT_N0 - 4L*CVT_N1; }
    float4 v = *(const float4*)(src + off);
    ushort4 o; o.x = f2bf(v.x); o.y = f2bf(v.y); o.z = f2bf(v.z); o.w = f2bf(v.w);
    *(ushort4*)(dst + i) = o;
}

// ---------------- embedding: write fp32 + bf16 ----------------
__global__ void embed_kernel(const int* __restrict__ tok, const float* __restrict__ emb,
                             float* __restrict__ xf, unsigned short* __restrict__ xb) {
    int idx = blockIdx.x * blockDim.x + threadIdx.x;
    if (idx >= N_ * E_) return;
    int n = idx >> 9;
    int e = idx & (E_ - 1);
    float v = emb[tok[n] * E_ + e];
    xf[idx] = v; xb[idx] = f2bf(v);
}

// ---------------- MFMA GEMM: BM=64, BN=64, paired K-chunks, XCD-grouped ------
// 4 LDS buffers; stage the next PAIR of 64-wide K-chunks while computing the
// current pair -> one __syncthreads per 32 MFMAs. 64 KB LDS = 2 blocks/CU.
template<int RELU, int WF, int WB>
__global__ __launch_bounds__(256) void gemm64(
    const unsigned short* __restrict__ A, const unsigned short* __restrict__ W,
    const float* __restrict__ bias, float* __restrict__ Cf, unsigned short* __restrict__ Cb,
    int M, int Nout, int K)
{
    __shared__ unsigned short Asm[4][64 * 64];   // 4 x 8 KB, swizzled
    __shared__ unsigned short Bsm[4][64 * 64];   // 4 x 8 KB, swizzled
    int tid = threadIdx.x;
    int wv = tid >> 6, ln = tid & 63;
    int lquad = ln >> 4, lmod = ln & 15;
    int mstrip, nblk;
    xcd_remap(mstrip, nblk);
    int m0 = mstrip * 64, n0 = nblk * 64;

    floatx4 acc[4] = {};

    auto stage = [&](int k0, int s) {
        // lane fetches the chunk whose swizzled home is its fixed LDS slot:
        // k8_src = k8_dest ^ (row & 7)
        #pragma unroll
        for (int c = 0; c < 2; ++c) {
            int cc = tid + 256 * c;
            int r = cc >> 3, k8s = (cc & 7) ^ (r & 7);
            gload_lds16(A + (size_t)(m0 + r) * K + k0 + 8 * k8s,
                        &Asm[s][2048 * c + 512 * wv]);
        }
        #pragma unroll
        for (int c = 0; c < 2; ++c) {
            int cc = tid + 256 * c;
            int r = cc >> 3, k8s = (cc & 7) ^ (r & 7);
            gload_lds16(W + (size_t)(n0 + r) * K + k0 + 8 * k8s,
                        &Bsm[s][2048 * c + 512 * wv]);
        }
    };

    int np = K >> 7;                       // pairs of 64-chunks (K=512 -> 4)
    stage(0, 0);
    stage(64, 1);
    __syncthreads();

    for (int t = 0; t < np; ++t) {
        if (t + 1 < np) {
            stage((2 * t + 2) << 6, (2 * t + 2) & 3);
            stage((2 * t + 3) << 6, (2 * t + 3) & 3);
        }
        #pragma unroll
        for (int half = 0; half < 2; ++half) {
            int s = (2 * t + half) & 3;
            #pragma unroll
            for (int ks = 0; ks < 2; ++ks) {
                bf16x8 af = *(const bf16x8*)&Asm[s][SW(16 * wv + lmod, ks * 4 + lquad)];
                #pragma unroll
                for (int j = 0; j < 4; ++j) {
                    bf16x8 bfr = *(const bf16x8*)&Bsm[s][SW(16 * j + lmod, ks * 4 + lquad)];
                    acc[j] = __builtin_amdgcn_mfma_f32_16x16x32_bf16(af, bfr, acc[j], 0, 0, 0);
                }
            }
        }
        if (t + 1 < np) __syncthreads();   // drains next-pair prefetch + WAR
    }

    #pragma unroll
    for (int j = 0; j < 4; ++j) {
        int n = n0 + 16 * j + lmod;
        float bj = bias[n];
        #pragma unroll
        for (int v = 0; v < 4; ++v) {
            int m = m0 + 16 * wv + 4 * lquad + v;
            float val = acc[j][v] + bj;
            if (RELU) val = fmaxf(val, 0.f);
            if (WF) Cf[(size_t)m * Nout + n] = val;
            if (WB) Cb[(size_t)m * Nout + n] = f2bf(val);
        }
    }
}

// ---------------- QKV GEMM with fused V-transpose (vprep), XCD-grouped -------
// BM=128. Blocks with n0%192==128 are pure-V blocks: instead of writing qkv_bf
// (dead for V), they write vt_g[bh][d][t] transposed from accumulators and
// reduce the per-ktile column sums into vtile[bh][kt][d].
__global__ __launch_bounds__(256) void gemm_qkv(
    const unsigned short* __restrict__ A, const unsigned short* __restrict__ W,
    const float* __restrict__ bias, unsigned short* __restrict__ Cb,
    unsigned short* __restrict__ vt_g, float* __restrict__ vtile, int K)
{
    __shared__ unsigned short Asm[2][128 * 64];
    __shared__ unsigned short Bsm[2][64 * 64];
    __shared__ float vred[4][64];
    int tid = threadIdx.x;
    int wv = tid >> 6, ln = tid & 63;
    int lquad = ln >> 4, lmod = ln & 15;
    int mstrip, nblk;
    xcd_remap(mstrip, nblk);
    int m0 = mstrip * 128, n0 = nblk * 64;

    floatx4 acc[2][4] = {};

    auto stage = [&](int k0, int pb) {
        #pragma unroll
        for (int c = 0; c < 4; ++c) {
            int cc = tid + 256 * c;
            int r = cc >> 3, k8s = (cc & 7) ^ (r & 7);
            gload_lds16(A + (size_t)(m0 + r) * K + k0 + 8 * k8s,
                        &Asm[pb][2048 * c + 512 * wv]);
        }
        #pragma unroll
        for (int c = 0; c < 2; ++c) {
            int cc = tid + 256 * c;
            int r = cc >> 3, k8s = (cc & 7) ^ (r & 7);
            gload_lds16(W + (size_t)(n0 + r) * K + k0 + 8 * k8s,
                        &Bsm[pb][2048 * c + 512 * wv]);
        }
    };

    int nt = K >> 6;
    stage(0, 0);
    __syncthreads();
    for (int t = 0; t < nt; ++t) {
        int pb = t & 1;
        if (t + 1 < nt) stage((t + 1) << 6, pb ^ 1);
        #pragma unroll
        for (int ks = 0; ks < 2; ++ks) {
            bf16x8 af[2], bfr[4];
            #pragma unroll
            for (int i = 0; i < 2; ++i)
                af[i] = *(const bf16x8*)&Asm[pb][SW(32 * wv + 16 * i + lmod, ks * 4 + lquad)];
            #pragma unroll
            for (int j = 0; j < 4; ++j)
                bfr[j] = *(const bf16x8*)&Bsm[pb][SW(16 * j + lmod, ks * 4 + lquad)];
            #pragma unroll
            for (int i = 0; i < 2; ++i)
                #pragma unroll
                for (int j = 0; j < 4; ++j)
                    acc[i][j] = __builtin_amdgcn_mfma_f32_16x16x32_bf16(af[i], bfr[j], acc[i][j], 0, 0, 0);
        }
        if (t + 1 < nt) __syncthreads();
    }

    if ((n0 % 192) != 128) {
        #pragma unroll
        for (int i = 0; i < 2; ++i)
            #pragma unroll
            for (int j = 0; j < 4; ++j) {
                int n = n0 + 16 * j + lmod;
                float bj = bias[n];
                #pragma unroll
                for (int v = 0; v < 4; ++v) {
                    int m = m0 + 32 * wv + 16 * i + 4 * lquad + v;
                    Cb[(size_t)m * E3_ + n] = f2bf(acc[i][j][v] + bj);
                }
            }
    } else {
        // pure-V block: write transposed vt_g + vtile sums
        int h = n0 / 192;
        int b = m0 >> 10;
        int bh = b * 8 + h;
        int t0 = m0 & 1023;
        int kt0 = t0 >> 6;
        float sj[4] = {0.f, 0.f, 0.f, 0.f};
        #pragma unroll
        for (int j = 0; j < 4; ++j) {
            float bj = bias[n0 + 16 * j + lmod];
            #pragma unroll
            for (int i = 0; i < 2; ++i) {
                union { unsigned short u[4]; uint2 q; } pk;
                #pragma unroll
                for (int v = 0; v < 4; ++v) {
                    unsigned short r = f2bf(acc[i][j][v] + bj);
                    pk.u[v] = r;
                    sj[j] += bf2f(r);
                }
                int t = t0 + 32 * wv + 16 * i + 4 * lquad;
                *(uint2*)&vt_g[((size_t)(bh * 64 + 16 * j + lmod)) * T_ + t] = pk.q;
            }
        }
        #pragma unroll
        for (int j = 0; j < 4; ++j) {
            sj[j] += __shfl_xor(sj[j], 16);
            sj[j] += __shfl_xor(sj[j], 32);
        }
        if (lquad == 0) {
            #pragma unroll
            for (int j = 0; j < 4; ++j) vred[wv][16 * j + lmod] = sj[j];
        }
        __syncthreads();
        if (tid < 128) {
            int half = tid >> 6, d = tid & 63;
            vtile[((size_t)bh * 16 + kt0 + half) * 64 + d] =
                vred[2 * half][d] + vred[2 * half + 1][d];
        }
    }
}

// ---------------- MFMA flash attention, depth-1 pipelined --------------------
// Grid (32 bh, 16); 2 blocks/CU. qt remap y<8?y:23-y so colocated pairs
// (i, i+256) carry complementary (qt, 15-qt) = 17 tiles. Masked scores are
// ZERO (=> p = 1). Ps is wave-private: softmax->PV needs only lgkmcnt(0),
// no s_barrier.
__global__ __launch_bounds__(256) void attn_mfma(const unsigned short* __restrict__ qkv,
                                                 const unsigned short* __restrict__ vt_g,
                                                 const float* __restrict__ vtile,
                                                 unsigned short* __restrict__ outb)
{
    __shared__ unsigned short Qs[64 * 64];       // [q][d] swizzled
    __shared__ unsigned short Ks[2][64 * 64];    // [k][d] swizzled, dbuf
    __shared__ unsigned short Vs[2][64 * 64];    // [d][k] swizzled, dbuf
    __shared__ unsigned short Ps[64 * 64];       // [q][k] swizzled, wave-private rows

    int tid = threadIdx.x;
    int wv = tid >> 6, ln = tid & 63;
    int lquad = ln >> 4, lmod = ln & 15;
    int bh = blockIdx.x;
    int y = blockIdx.y;
    int qt = (y < 8) ? y : 23 - y;               // complementary pairing
    int b = bh >> 3, h = bh & 7;
    int q0 = qt * 64;
    const float scale = 0.125f;
    size_t base = (size_t)b * T_ * E3_ + h * 192;

    auto stageKV = [&](int k0, int pb) {
        #pragma unroll
        for (int c = 0; c < 2; ++c) {
            int cc = tid + 256 * c;
            int r = cc >> 3, k8s = (cc & 7) ^ (r & 7);
            gload_lds16(qkv + base + (size_t)(k0 + r) * E3_ + 64 + 8 * k8s,
                        &Ks[pb][2048 * c + 512 * wv]);
            gload_lds16(vt_g + ((size_t)(bh * 64 + r)) * T_ + k0 + 8 * k8s,
                        &Vs[pb][2048 * c + 512 * wv]);
        }
    };

    // stage Q + first K/V tile, then one drain
    #pragma unroll
    for (int c = 0; c < 2; ++c) {
        int cc = tid + 256 * c;
        int r = cc >> 3, k8s = (cc & 7) ^ (r & 7);
        gload_lds16(qkv + base + (size_t)(q0 + r) * E3_ + 8 * k8s, Qs + 2048 * c + 512 * wv);
    }
    stageKV(0, 0);
    __syncthreads();

    float lrow[4] = {0.f, 0.f, 0.f, 0.f};
    floatx4 Oa[4] = {};

    for (int kt = 0; kt <= qt; ++kt) {
        int pb = kt & 1;
        int k0 = kt * 64;
        if (kt < qt) stageKV(k0 + 64, pb ^ 1);    // prefetch next K/V tile

        floatx4 sacc[4] = {};
        #pragma unroll
        for (int ks = 0; ks < 2; ++ks) {
            bf16x8 aq = *(const bf16x8*)&Qs[SW(16 * wv + lmod, ks * 4 + lquad)];
            #pragma unroll
            for (int j = 0; j < 4; ++j) {
                bf16x8 bk = *(const bf16x8*)&Ks[pb][SW(16 * j + lmod, ks * 4 + lquad)];
                sacc[j] = __builtin_amdgcn_mfma_f32_16x16x32_bf16(aq, bk, sacc[j], 0, 0, 0);
            }
        }
        #pragma unroll
        for (int v = 0; v < 4; ++v) {
            int qg = q0 + 16 * wv + 4 * lquad + v;
            int row = 16 * wv + 4 * lquad + v;
            #pragma unroll
            for (int j = 0; j < 4; ++j) {
                int kg = k0 + 16 * j + lmod;
                float p = (kg <= qg) ? __expf(sacc[j][v] * scale) : 1.0f;
                lrow[v] += p;
                int col = 16 * j + lmod;
                Ps[SW(row, col >> 3) + (col & 7)] = f2bf(p);
            }
        }
        // Ps rows are wave-private: only this wave's DS writes must drain.
        asm volatile("s_waitcnt lgkmcnt(0)" ::: "memory");
        __builtin_amdgcn_sched_barrier(0);

        #pragma unroll
        for (int ks = 0; ks < 2; ++ks) {
            bf16x8 ap = *(const bf16x8*)&Ps[SW(16 * wv + lmod, ks * 4 + lquad)];
            #pragma unroll
            for (int f = 0; f < 4; ++f) {
                bf16x8 bv = *(const bf16x8*)&Vs[pb][SW(16 * f + lmod, ks * 4 + lquad)];
                Oa[f] = __builtin_amdgcn_mfma_f32_16x16x32_bf16(ap, bv, Oa[f], 0, 0, 0);
            }
        }
        if (kt < qt) __syncthreads();  // drain prefetch + WAR on Ks/Vs
    }

    #pragma unroll
    for (int v = 0; v < 4; ++v)
        #pragma unroll
        for (int msk = 1; msk < 16; msk <<= 1) lrow[v] += __shfl_xor(lrow[v], msk);

    if (qt < 15) {
        float Km = (float)((15 - qt) * 64);
        #pragma unroll
        for (int v = 0; v < 4; ++v) lrow[v] += Km;
        #pragma unroll
        for (int f = 0; f < 4; ++f) {
            float sv = 0.f;
            for (int kt = qt + 1; kt < 16; ++kt)
                sv += vtile[((size_t)bh * 16 + kt) * 64 + 16 * f + lmod];
            #pragma unroll
            for (int v = 0; v < 4; ++v) Oa[f][v] += sv;
        }
    }

    #pragma unroll
    for (int f = 0; f < 4; ++f)
        #pragma unroll
        for (int v = 0; v < 4; ++v) {
            int q = q0 + 16 * wv + 4 * lquad + v;
            outb[(size_t)(b * T_ + q) * E_ + h * DH_ + 16 * f + lmod] = f2bf(Oa[f][v] / lrow[v]);
        }
}

// ---------------- residual add + LN: wave-per-row ----------------
__global__ __launch_bounds__(256) void add_ln_kernel(
    const float* __restrict__ a, const float* __restrict__ r,
    const float* __restrict__ s, const float* __restrict__ bpar,
    float* __restrict__ outF, unsigned short* __restrict__ outB)
{
    int tid = threadIdx.x, wv = tid >> 6, ln = tid & 63;
    int n = blockIdx.x * 4 + wv;
    int e = ln * 8;
    size_t base = (size_t)n * E_ + e;
    float4 a0 = *(const float4*)&a[base],     a1 = *(const float4*)&a[base + 4];
    float4 r0 = *(const float4*)&r[base],     r1 = *(const float4*)&r[base + 4];
    float v[8] = {a0.x + r0.x, a0.y + r0.y, a0.z + r0.z, a0.w + r0.w,
                  a1.x + r1.x, a1.y + r1.y, a1.z + r1.z, a1.w + r1.w};

    float sm = 0.f;
    #pragma unroll
    for (int i = 0; i < 8; ++i) sm += v[i];
    #pragma unroll
    for (int msk = 1; msk < 64; msk <<= 1) sm += __shfl_xor(sm, msk);
    float mu = sm * (1.f / 512.f);

    float ss = 0.f;
    #pragma unroll
    for (int i = 0; i < 8; ++i) { v[i] -= mu; ss += v[i] * v[i]; }
    #pragma unroll
    for (int msk = 1; msk < 64; msk <<= 1) ss += __shfl_xor(ss, msk);
    float rstd = rsqrtf(ss * (1.f / 512.f) + 1e-5f);

    float4 sc0 = *(const float4*)&s[e],    sc1 = *(const float4*)&s[e + 4];
    float4 bp0 = *(const float4*)&bpar[e], bp1 = *(const float4*)&bpar[e + 4];
    float o[8];
    o[0] = v[0] * rstd * sc0.x + bp0.x; o[1] = v[1] * rstd * sc0.y + bp0.y;
    o[2] = v[2] * rstd * sc0.z + bp0.z; o[3] = v[3] * rstd * sc0.w + bp0.w;
    o[4] = v[4] * rstd * sc1.x + bp1.x; o[5] = v[5] * rstd * sc1.y + bp1.y;
    o[6] = v[6] * rstd * sc1.z + bp1.z; o[7] = v[7] * rstd * sc1.w + bp1.w;
    *(float4*)&outF[base]     = make_float4(o[0], o[1], o[2], o[3]);
    *(float4*)&outF[base + 4] = make_float4(o[4], o[5], o[6], o[7]);
    union { unsigned short u[8]; uint4 q; } pk;
    #pragma unroll
    for (int i = 0; i < 8; ++i) pk.u[i] = f2bf(o[i]);
    *(uint4*)&outB[base] = pk.q;
}

// ---------------- head GEMM + fused per-row loss ------------------------------
// BM=64, BN=128 (full vocab row per block) -> grid 64. Each wave owns full
// rows, so max/sum/target-gather happen in-wave; writes logits + rowloss.
__global__ __launch_bounds__(256) void head_loss_kernel(
    const unsigned short* __restrict__ A, const unsigned short* __restrict__ W,
    const float* __restrict__ bias, const int* __restrict__ tgt,
    float* __restrict__ out_logits, float* __restrict__ rowloss)
{
    __shared__ unsigned short Asm[2][64 * 64];    // 2 x 8 KB
    __shared__ unsigned short Bsm[2][128 * 64];   // 2 x 16 KB
    int tid = threadIdx.x;
    int wv = tid >> 6, ln = tid & 63;
    int lquad = ln >> 4, lmod = ln & 15;
    int m0 = blockIdx.x * 64;

    floatx4 acc[8] = {};

    auto stage = [&](int k0, int pb) {
        #pragma unroll
        for (int c = 0; c < 2; ++c) {
            int cc = tid + 256 * c;
            int r = cc >> 3, k8s = (cc & 7) ^ (r & 7);
            gload_lds16(A + (size_t)(m0 + r) * E_ + k0 + 8 * k8s,
                        &Asm[pb][2048 * c + 512 * wv]);
        }
        #pragma unroll
        for (int c = 0; c < 4; ++c) {
            int cc = tid + 256 * c;
            int r = cc >> 3, k8s = (cc & 7) ^ (r & 7);
            gload_lds16(W + (size_t)r * E_ + k0 + 8 * k8s,
                        &Bsm[pb][2048 * c + 512 * wv]);
        }
    };

    stage(0, 0);
    __syncthreads();
    for (int t = 0; t < 8; ++t) {
        int pb = t & 1;
        if (t < 7) stage((t + 1) << 6, pb ^ 1);
        #pragma unroll
        for (int ks = 0; ks < 2; ++ks) {
            bf16x8 af = *(const bf16x8*)&Asm[pb][SW(16 * wv + lmod, ks * 4 + lquad)];
            #pragma unroll
            for (int j = 0; j < 8; ++j) {
                bf16x8 bf = *(const bf16x8*)&Bsm[pb][SW(16 * j + lmod, ks * 4 + lquad)];
                acc[j] = __builtin_amdgcn_mfma_f32_16x16x32_bf16(af, bf, acc[j], 0, 0, 0);
            }
        }
        if (t < 7) __syncthreads();
    }

    float bj[8];
    #pragma unroll
    for (int j = 0; j < 8; ++j) bj[j] = bias[16 * j + lmod];
    #pragma unroll
    for (int v = 0; v < 4; ++v) {
        int m = m0 + 16 * wv + 4 * lquad + v;
        float x[8];
        float mx = -1e30f, sx = 0.f;
        #pragma unroll
        for (int j = 0; j < 8; ++j) {
            x[j] = acc[j][v] + bj[j];
            out_logits[(size_t)m * V_ + 16 * j + lmod] = x[j];
            mx = fmaxf(mx, x[j]); sx += x[j];
        }
        #pragma unroll
        for (int msk = 1; msk < 16; msk <<= 1) mx = fmaxf(mx, __shfl_xor(mx, msk));
        float se = 0.f;
        #pragma unroll
        for (int j = 0; j < 8; ++j) se += __expf(x[j] - mx);
        #pragma unroll
        for (int msk = 1; msk < 16; msk <<= 1) {
            se += __shfl_xor(se, msk);
            sx += __shfl_xor(sx, msk);
        }
        int t = tgt[m];                          // uniform within the 16-group
        float cand = 0.f;
        #pragma unroll
        for (int j = 0; j < 8; ++j) cand = ((t >> 4) == j) ? x[j] : cand;
        float xt = __shfl(cand, (ln & 48) | (t & 15));
        if (lmod == 0) {
            float lse = mx + __logf(se);
            rowloss[m] = 0.9f * (lse - xt) + 0.1f * (lse - sx * (1.f / 128.f));
        }
    }
}

__global__ __launch_bounds__(256) void loss_reduce_kernel(
    const float* __restrict__ rowloss, float* __restrict__ out)
{
    int tid = threadIdx.x;
    float sm = 0.f;
    for (int idx = tid; idx < N_; idx += 256) sm += rowloss[idx];
    #pragma unroll
    for (int off = 32; off; off >>= 1) sm += __shfl_down(sm, off, 64);
    __shared__ float red[4];
    int lane = tid & 63, w = tid >> 6;
    if (lane == 0) red[w] = sm;
    __syncthreads();
    if (tid == 0) out[0] = (red[0] + red[1] + red[2] + red[3]) * (1.f / (float)N_);
}

extern "C" void kernel_launch(void* const* d_in, const int* in_sizes, int n_in,
                              void* d_out, int out_size, void* d_ws, size_t ws_size,
                              hipStream_t stream)
{
    (void)in_sizes; (void)n_in; (void)out_size; (void)ws_size;
    const int* toks     = (const int*)d_in[0];
    const int* tgts     = (const int*)d_in[1];
    const float* emb    = (const float*)d_in[2];
    const float* qkv_w  = (const float*)d_in[3];
    const float* qkv_b  = (const float*)d_in[4];
    const float* aff1_w = (const float*)d_in[5];
    const float* aff1_b = (const float*)d_in[6];
    const float* aff2_w = (const float*)d_in[7];
    const float* aff2_b = (const float*)d_in[8];
    const float* ffn1_w = (const float*)d_in[9];
    const float* ffn1_b = (const float*)d_in[10];
    const float* ffn2_w = (const float*)d_in[11];
    const float* ffn2_b = (const float*)d_in[12];
    const float* ln1_s  = (const float*)d_in[13];
    const float* ln1_b  = (const float*)d_in[14];
    const float* ln2_s  = (const float*)d_in[15];
    const float* ln2_b  = (const float*)d_in[16];
    const float* head_w = (const float*)d_in[17];
    const float* head_b = (const float*)d_in[18];

    char* p = (char*)d_ws;
    auto carve = [&](size_t bytes) { char* r = p; p += (bytes + 255) & ~(size_t)255; return (void*)r; };
    unsigned short* wb_all  = (unsigned short*)carve((size_t)CVT_TOT * 2);
    unsigned short* wb_qkv  = wb_all;
    unsigned short* wb_aff1 = wb_qkv  + (size_t)CVT_N0;
    unsigned short* wb_aff2 = wb_aff1 + (size_t)CVT_N1;
    unsigned short* wb_ffn1 = wb_aff2 + (size_t)CVT_N1;
    unsigned short* wb_ffn2 = wb_ffn1 + (size_t)CVT_N1;
    unsigned short* wb_head = wb_ffn2 + (size_t)CVT_N1;
    float*          x_f     = (float*)carve((size_t)N_ * E_ * 4);
    unsigned short* x_b     = (unsigned short*)carve((size_t)N_ * E_ * 2);
    unsigned short* qkv_bf  = (unsigned short*)carve((size_t)N_ * E3_ * 2);
    unsigned short* att_b   = (unsigned short*)carve((size_t)N_ * E_ * 2);
    unsigned short* h_b     = (unsigned short*)carve((size_t)N_ * E_ * 2);
    float*          y_f     = (float*)carve((size_t)N_ * E_ * 4);
    float*          o1_f    = (float*)carve((size_t)N_ * E_ * 4);
    unsigned short* o1_b    = (unsigned short*)carve((size_t)N_ * E_ * 2);
    float*          rowl    = (float*)carve((size_t)N_ * 4);
    float*          vtile   = (float*)carve((size_t)32 * 16 * 64 * 4);
    unsigned short* vt_g    = (unsigned short*)carve((size_t)32 * 64 * T_ * 2);  // 4 MB

    float* out_logits = (float*)d_out;
    float* out_loss   = out_logits + (size_t)N_ * V_;

    cvt_all_kernel<<<dim3(CVT_TOT / 1024), 256, 0, stream>>>(
        qkv_w, aff1_w, aff2_w, ffn1_w, ffn2_w, head_w, wb_all);

    embed_kernel<<<dim3((N_ * E_) / 256), 256, 0, stream>>>(toks, emb, x_f, x_b);

    for (int l = 0; l < L_; ++l) {
        gemm_qkv<<<dim3(E3_/64, N_/128), 256, 0, stream>>>(
            x_b, wb_qkv + (size_t)l * E3_ * E_, qkv_b + (size_t)l * E3_,
            qkv_bf, vt_g, vtile, E_);
        attn_mfma<<<dim3(32, 16), 256, 0, stream>>>(qkv_bf, vt_g, vtile, att_b);
        gemm64<1,0,1><<<dim3(E_/64, N_/64), 256, 0, stream>>>(
            att_b, wb_aff1 + (size_t)l * E_ * E_, aff1_b + (size_t)l * E_,
            nullptr, h_b, N_, E_, E_);
        gemm64<0,1,0><<<dim3(E_/64, N_/64), 256, 0, stream>>>(
            h_b, wb_aff2 + (size_t)l * E_ * E_, aff2_b + (size_t)l * E_,
            y_f, nullptr, N_, E_, E_);
        add_ln_kernel<<<dim3(N_/4), 256, 0, stream>>>(
            y_f, x_f, ln1_s + (size_t)l * E_, ln1_b + (size_t)l * E_, o1_f, o1_b);
        gemm64<1,0,1><<<dim3(E_/64, N_/64), 256, 0, stream>>>(
            o1_b, wb_ffn1 + (size_t)l * E_ * E_, ffn1_b + (size_t)l * E_,
            nullptr, h_b, N_, E_, E_);
        gemm64<0,1,0><<<dim3(E_/64, N_/64), 256, 0, stream>>>(
            h_b, wb_ffn2 + (size_t)l * E_ * E_, ffn2_b + (size_t)l * E_,
            y_f, nullptr, N_, E_, E_);
        add_ln_kernel<<<dim3(N_/4), 256, 0, stream>>>(
            o1_f, y_f, ln2_s + (size_t)l * E_, ln2_b + (size_t)l * E_, x_f, x_b);
    }

    head_loss_kernel<<<dim3(N_/64), 256, 0, stream>>>(
        x_b, wb_head, head_b, tgts, out_logits, rowl);
    loss_reduce_kernel<<<dim3(1), 256, 0, stream>>>(rowl, out_loss);
}